// Round 4
// baseline (559.974 us; speedup 1.0000x reference)
//
#include <hip/hip_runtime.h>

#define T_LEN   131072
#define IN_DIM  256
#define HD      64
#define PD      32
#define NLAY    4
#define CHUNK   128
#define NBLK    (T_LEN / CHUNK)   // 1024

// ---------------------------------------------------------------- K0: setup
__global__ __launch_bounds__(512) void ssm_k0_setup(
    const float* __restrict__ Lre, const float* __restrict__ Lim,
    const float* __restrict__ logstep,
    const float* __restrict__ Bre, const float* __restrict__ Bim,
    const float* __restrict__ Cre, const float* __restrict__ Cim,
    const float* __restrict__ w1, const float* __restrict__ w2,
    const float* __restrict__ enc_w, const int* __restrict__ gptr,
    float* __restrict__ Lbar, float* __restrict__ Ldt,
    float* __restrict__ Bbar_t, float* __restrict__ Ct,
    float* __restrict__ w1t, float* __restrict__ w2t,
    float* __restrict__ wenc, float* __restrict__ stats)
{
    __shared__ float fact[NLAY * PD * 2];
    int tid = threadIdx.x;
    if (tid < NLAY * PD) {
        int l = tid >> 5, p = tid & 31;
        float dt = expf(logstep[l * PD + p]);
        float lr = Lre[l * PD + p], li = Lim[l * PD + p];
        float ldr = lr * dt, ldi = li * dt;
        Ldt[tid * 2] = ldr; Ldt[tid * 2 + 1] = ldi;
        float e = expf(ldr);
        float sn, cs; sincosf(ldi, &sn, &cs);
        float lbr = e * cs, lbi = e * sn;
        Lbar[tid * 2] = lbr; Lbar[tid * 2 + 1] = lbi;
        float den = lr * lr + li * li;
        float nr = lbr - 1.0f, ni = lbi;
        fact[tid * 2]     = (nr * lr + ni * li) / den;
        fact[tid * 2 + 1] = (ni * lr - nr * li) / den;
    }
    if (tid < NLAY * 128) stats[tid] = 0.0f;
    __syncthreads();
    // Bbar_t[l][c][2p] ; Ct planes [l][p][re:0..63 | im:64..127]
    for (int idx = tid; idx < NLAY * PD * HD; idx += 512) {
        int lp = idx >> 6; int c = idx & 63;
        int l = lp >> 5, p = lp & 31;
        float fr = fact[lp * 2], fi = fact[lp * 2 + 1];
        float br = Bre[idx], bi = Bim[idx];                    // B is [l][p][h]
        Bbar_t[((size_t)(l * HD + c)) * HD + 2 * p]     = fr * br - fi * bi;
        Bbar_t[((size_t)(l * HD + c)) * HD + 2 * p + 1] = fr * bi + fi * br;
        Ct[((size_t)(l * PD + p)) * 128 + c]      = Cre[(l * HD + c) * PD + p];
        Ct[((size_t)(l * PD + p)) * 128 + 64 + c] = Cim[(l * HD + c) * PD + p];
    }
    for (int idx = tid; idx < NLAY * HD * HD; idx += 512) {
        int l = idx >> 12; int k = (idx >> 6) & 63; int c = idx & 63;
        w1t[idx] = w1[(l * HD + c) * HD + k];
        w2t[idx] = w2[(l * HD + c) * HD + k];
    }
    int g = gptr[0];
    for (int idx = tid; idx < IN_DIM * HD; idx += 512) {
        int k = idx >> 6, ch = idx & 63;
        wenc[idx] = (ch < 56) ? enc_w[((size_t)(g * 56 + ch)) * IN_DIM + k] : 0.0f;
    }
}

// ---------------------------------------------------------------- K1: encoder
// 512 threads = 8 waves; wave = (cg = wid&3, rowhalf = wid>>2); lane = row-in-half.
// x staged in LDS (stride 66, float2); weights via wave-uniform s_load.
__global__ __launch_bounds__(512, 4) void ssm_k1_encoder(
    const float* __restrict__ x, const int* __restrict__ gptr,
    const float* __restrict__ wenc, const float* __restrict__ enc_b,
    const float* __restrict__ ctx_emb,
    float* __restrict__ h, float* __restrict__ stats)
{
    __shared__ float xl[128 * 66];
    __shared__ float sp1[128], sp2[128];
    int tid = threadIdx.x;
    int lane = tid & 63, wid = tid >> 6;
    int ucg = __builtin_amdgcn_readfirstlane(wid & 3);
    int row = (wid >> 2) * 64 + lane;
    int g = gptr[0];
    size_t r0 = (size_t)blockIdx.x * 128;

    float acc[16];
#pragma unroll
    for (int i = 0; i < 16; ++i) {
        int ch = ucg * 16 + i;                      // wave-uniform guard
        acc[i] = (ch < 56) ? enc_b[g * 56 + ch] : 0.0f;
    }

    for (int kt = 0; kt < 4; ++kt) {
        __syncthreads();
#pragma unroll
        for (int it = 0; it < 8; ++it) {
            int idx = it * 512 + tid;               // 4096 float2 = 128 rows x 64 cols
            int rr = idx >> 5, c2 = idx & 31;
            *(float2*)&xl[rr * 66 + c2 * 2] =
                *(const float2*)&x[(r0 + rr) * IN_DIM + kt * 64 + c2 * 2];
        }
        __syncthreads();
        for (int k2 = 0; k2 < 32; ++k2) {
            float2 xv = *(float2*)&xl[row * 66 + 2 * k2];
            const float* wp = &wenc[(size_t)(kt * 64 + 2 * k2) * 64 + ucg * 16];  // uniform
            float4 a0 = *(const float4*)&wp[0],  a1 = *(const float4*)&wp[4];
            float4 a2 = *(const float4*)&wp[8],  a3 = *(const float4*)&wp[12];
            float4 b0 = *(const float4*)&wp[64], b1v = *(const float4*)&wp[68];
            float4 b2v = *(const float4*)&wp[72], b3 = *(const float4*)&wp[76];
            acc[0]  += xv.x * a0.x + xv.y * b0.x;   acc[1]  += xv.x * a0.y + xv.y * b0.y;
            acc[2]  += xv.x * a0.z + xv.y * b0.z;   acc[3]  += xv.x * a0.w + xv.y * b0.w;
            acc[4]  += xv.x * a1.x + xv.y * b1v.x;  acc[5]  += xv.x * a1.y + xv.y * b1v.y;
            acc[6]  += xv.x * a1.z + xv.y * b1v.z;  acc[7]  += xv.x * a1.w + xv.y * b1v.w;
            acc[8]  += xv.x * a2.x + xv.y * b2v.x;  acc[9]  += xv.x * a2.y + xv.y * b2v.y;
            acc[10] += xv.x * a2.z + xv.y * b2v.z;  acc[11] += xv.x * a2.w + xv.y * b2v.w;
            acc[12] += xv.x * a3.x + xv.y * b3.x;   acc[13] += xv.x * a3.y + xv.y * b3.y;
            acc[14] += xv.x * a3.z + xv.y * b3.z;   acc[15] += xv.x * a3.w + xv.y * b3.w;
        }
    }
    // ctx channels (56..63) override
    if (ucg == 3) {
#pragma unroll
        for (int i = 8; i < 16; ++i) acc[i] = ctx_emb[g * 8 + (i - 8)];
    }
    // write h (float4)
#pragma unroll
    for (int j4 = 0; j4 < 4; ++j4)
        *(float4*)&h[(r0 + row) * HD + ucg * 16 + j4 * 4] =
            make_float4(acc[j4 * 4], acc[j4 * 4 + 1], acc[j4 * 4 + 2], acc[j4 * 4 + 3]);
    // layer-0 stats: lanes of a wave are 64 distinct rows -> full-wave reduce
#pragma unroll
    for (int i = 0; i < 16; ++i) {
        float v1 = acc[i], v2 = acc[i] * acc[i];
#pragma unroll
        for (int m = 1; m < 64; m <<= 1) { v1 += __shfl_xor(v1, m, 64); v2 += __shfl_xor(v2, m, 64); }
        if (lane == 0) { sp1[wid * 16 + i] = v1; sp2[wid * 16 + i] = v2; }
    }
    __syncthreads();
    if (tid < 64) {
        atomicAdd(&stats[tid],      sp1[tid] + sp1[64 + tid]);
        atomicAdd(&stats[64 + tid], sp2[tid] + sp2[64 + tid]);
    }
}

// ---------------------------------------------------------------- K2: hn -> Bu -> local scan (unchanged)
__global__ __launch_bounds__(512, 4) void ssm_k2_bu_scan(
    const float* __restrict__ h, const float* __restrict__ stats,
    const float* __restrict__ nscale, const float* __restrict__ nbias,
    const float* __restrict__ Bbar_t, const float* __restrict__ Lbar,
    float* __restrict__ xs, float* __restrict__ carry, int l)
{
    __shared__ float buf[128 * 66];
    __shared__ float sa[HD], sb[HD];
    int tid = threadIdx.x;
    int lane = tid & 63, wid = tid >> 6;
    int ucg = __builtin_amdgcn_readfirstlane(wid & 3);
    int row = (wid >> 2) * 64 + lane;
    size_t r0 = (size_t)blockIdx.x * CHUNK;

    if (tid < HD) {
        float s1 = stats[l * 128 + tid], s2 = stats[l * 128 + 64 + tid];
        float mu = s1 * (1.0f / T_LEN);
        float var = fmaxf(s2 * (1.0f / T_LEN) - mu * mu, 0.0f);
        float sc = nscale[l * HD + tid] * rsqrtf(var + 1e-5f);
        sa[tid] = sc;
        sb[tid] = nbias[l * HD + tid] - mu * sc;
    }
    __syncthreads();

#pragma unroll
    for (int j4 = 0; j4 < 4; ++j4) {
        float4 hv = *(const float4*)&h[(r0 + row) * HD + ucg * 16 + j4 * 4];
        int c = ucg * 16 + j4 * 4;
        float2 a = make_float2(hv.x * sa[c]     + sb[c],     hv.y * sa[c + 1] + sb[c + 1]);
        float2 b = make_float2(hv.z * sa[c + 2] + sb[c + 2], hv.w * sa[c + 3] + sb[c + 3]);
        *(float2*)&buf[row * 66 + c]     = a;
        *(float2*)&buf[row * 66 + c + 2] = b;
    }
    __syncthreads();

    float bacc[16];
#pragma unroll
    for (int j = 0; j < 16; ++j) bacc[j] = 0.0f;
    for (int k2 = 0; k2 < 32; ++k2) {
        float2 hk = *(float2*)&buf[row * 66 + 2 * k2];
        const float* b0 = &Bbar_t[(size_t)l * 4096 + (2 * k2) * 64 + ucg * 16];
        const float* b1p = b0 + 64;
        float4 a0 = *(const float4*)&b0[0],  a1 = *(const float4*)&b0[4];
        float4 a2 = *(const float4*)&b0[8],  a3 = *(const float4*)&b0[12];
        float4 c0 = *(const float4*)&b1p[0], c1 = *(const float4*)&b1p[4];
        float4 c2 = *(const float4*)&b1p[8], c3 = *(const float4*)&b1p[12];
        bacc[0]  += hk.x * a0.x + hk.y * c0.x;  bacc[1]  += hk.x * a0.y + hk.y * c0.y;
        bacc[2]  += hk.x * a0.z + hk.y * c0.z;  bacc[3]  += hk.x * a0.w + hk.y * c0.w;
        bacc[4]  += hk.x * a1.x + hk.y * c1.x;  bacc[5]  += hk.x * a1.y + hk.y * c1.y;
        bacc[6]  += hk.x * a1.z + hk.y * c1.z;  bacc[7]  += hk.x * a1.w + hk.y * c1.w;
        bacc[8]  += hk.x * a2.x + hk.y * c2.x;  bacc[9]  += hk.x * a2.y + hk.y * c2.y;
        bacc[10] += hk.x * a2.z + hk.y * c2.z;  bacc[11] += hk.x * a2.w + hk.y * c2.w;
        bacc[12] += hk.x * a3.x + hk.y * c3.x;  bacc[13] += hk.x * a3.y + hk.y * c3.y;
        bacc[14] += hk.x * a3.z + hk.y * c3.z;  bacc[15] += hk.x * a3.w + hk.y * c3.w;
    }
    __syncthreads();
#pragma unroll
    for (int j2 = 0; j2 < 8; ++j2)
        *(float2*)&buf[row * 66 + ucg * 16 + 2 * j2] =
            make_float2(bacc[2 * j2], bacc[2 * j2 + 1]);
    __syncthreads();

    if (tid < 64) {
        int p = lane >> 1;
        float Lr = Lbar[(l * PD + p) * 2];
        float Lj = Lbar[(l * PD + p) * 2 + 1];
        float csn = (lane & 1) ? Lj : -Lj;
        float xv = 0.0f;
        for (int t = 0; t < CHUNK; ++t) {
            float b = buf[t * 66 + lane];
            float xo = __shfl_xor(xv, 1, 64);
            xv = Lr * xv + csn * xo + b;
            buf[t * 66 + lane] = xv;
        }
        carry[(size_t)blockIdx.x * 64 + lane] = xv;
    }
    __syncthreads();
#pragma unroll
    for (int j4 = 0; j4 < 4; ++j4) {
        float2 a = *(float2*)&buf[row * 66 + ucg * 16 + 4 * j4];
        float2 b = *(float2*)&buf[row * 66 + ucg * 16 + 4 * j4 + 2];
        *(float4*)&xs[(r0 + row) * HD + ucg * 16 + 4 * j4] = make_float4(a.x, a.y, b.x, b.y);
    }
}

// ---------------------------------------------------------------- K3: cross-chunk carry scan (unchanged)
__global__ __launch_bounds__(64) void ssm_k3_carry(
    const float* __restrict__ carry, const float* __restrict__ Ldt,
    float* __restrict__ pc, int l)
{
    int p = blockIdx.x;
    int lane = threadIdx.x;
    float ldr = Ldt[(l * PD + p) * 2], ldi = Ldt[(l * PD + p) * 2 + 1];
    float er = __expf(ldr * (float)CHUNK);
    float an = ldi * (float)CHUNK;
    float lcr = er * __cosf(an), lci = er * __sinf(an);   // L^CHUNK
    float cr[16], ci[16];
#pragma unroll
    for (int j = 0; j < 16; ++j) {
        cr[j] = carry[(size_t)(lane * 16 + j) * 64 + 2 * p];
        ci[j] = carry[(size_t)(lane * 16 + j) * 64 + 2 * p + 1];
    }
    float ur = 0.0f, ui = 0.0f;
#pragma unroll
    for (int j = 0; j < 16; ++j) {
        float nr = lcr * ur - lci * ui + cr[j];
        float ni = lcr * ui + lci * ur + ci[j];
        ur = nr; ui = ni;
    }
    float mr = lcr, mi = lci;
#pragma unroll
    for (int s = 0; s < 4; ++s) { float t = mr * mr - mi * mi; mi = 2.0f * mr * mi; mr = t; }
#pragma unroll
    for (int d = 1; d < 64; d <<= 1) {
        float tr = __shfl_up(ur, d, 64);
        float ti = __shfl_up(ui, d, 64);
        if (lane >= d) { ur = mr * tr - mi * ti + ur; ui = mr * ti + mi * tr + ui; }
        float t = mr * mr - mi * mi; mi = 2.0f * mr * mi; mr = t;
    }
    float pr = __shfl_up(ur, 1, 64), pi = __shfl_up(ui, 1, 64);
    float xr = (lane == 0) ? 0.0f : pr;
    float xi = (lane == 0) ? 0.0f : pi;
#pragma unroll
    for (int j = 0; j < 16; ++j) {
        pc[(size_t)(lane * 16 + j) * 64 + 2 * p]     = xr;
        pc[(size_t)(lane * 16 + j) * 64 + 2 * p + 1] = xi;
        float nr = lcr * xr - lci * xi + cr[j];
        float ni = lcr * xi + lci * xr + ci[j];
        xr = nr; xi = ni;
    }
}

// ---------------------------------------------------------------- K4: fixup + C-proj + gelu + GLU + residual (+stats / decoder) (unchanged)
template <bool LAST>
__global__ __launch_bounds__(512, 4) void ssm_k4_out(
    const float* __restrict__ h, const float* __restrict__ xs,
    const float* __restrict__ pc, const float* __restrict__ stats,
    const float* __restrict__ nscale, const float* __restrict__ nbias,
    const float* __restrict__ Ldt, const float* __restrict__ Ct,
    const float* __restrict__ Dv,
    const float* __restrict__ w1t, const float* __restrict__ b1,
    const float* __restrict__ w2t, const float* __restrict__ b2,
    float* __restrict__ hout, float* __restrict__ stats_next,
    const float* __restrict__ dec_w, const float* __restrict__ dec_b,
    float* __restrict__ outp, int l)
{
    __shared__ float buf[128 * 66];
    __shared__ float sa[HD], sb[HD];
    __shared__ float sp1[128], sp2[128];
    int tid = threadIdx.x;
    int lane = tid & 63, wid = tid >> 6;
    int ucg = __builtin_amdgcn_readfirstlane(wid & 3);
    int row = (wid >> 2) * 64 + lane;
    size_t r0 = (size_t)blockIdx.x * CHUNK;

    if (tid < HD) {
        float s1 = stats[l * 128 + tid], s2 = stats[l * 128 + 64 + tid];
        float mu = s1 * (1.0f / T_LEN);
        float var = fmaxf(s2 * (1.0f / T_LEN) - mu * mu, 0.0f);
        float sc = nscale[l * HD + tid] * rsqrtf(var + 1e-5f);
        sa[tid] = sc;
        sb[tid] = nbias[l * HD + tid] - mu * sc;
    }

    float xf[16];
#pragma unroll
    for (int j4 = 0; j4 < 4; ++j4)
        *(float4*)&xf[j4 * 4] = *(const float4*)&xs[(r0 + row) * HD + ucg * 16 + j4 * 4];
    {
        const float* ldp = &Ldt[(l * PD + ucg * 8) * 2];                // uniform
        const float* pcp = &pc[(size_t)blockIdx.x * 64 + ucg * 16];     // uniform
        float tt = (float)(row + 1);
#pragma unroll
        for (int pp = 0; pp < 8; ++pp) {
            float e = __expf(ldp[2 * pp] * tt);
            float an = ldp[2 * pp + 1] * tt;
            float prr = e * __cosf(an), pri = e * __sinf(an);
            float pr_ = pcp[2 * pp], pi_ = pcp[2 * pp + 1];
            xf[2 * pp]     += prr * pr_ - pri * pi_;
            xf[2 * pp + 1] += prr * pi_ + pri * pr_;
        }
    }
#pragma unroll
    for (int j2 = 0; j2 < 8; ++j2)
        *(float2*)&buf[row * 66 + ucg * 16 + 2 * j2] =
            make_float2(xf[2 * j2], xf[2 * j2 + 1]);
    __syncthreads();

    float y[16];
#pragma unroll
    for (int i = 0; i < 16; ++i) y[i] = 0.0f;
    for (int p = 0; p < 32; ++p) {
        float2 xv = *(float2*)&buf[row * 66 + 2 * p];
        const float* cp = &Ct[(size_t)l * 4096 + p * 128 + ucg * 16];   // uniform
        float4 r0v = *(const float4*)&cp[0],  r1v = *(const float4*)&cp[4];
        float4 r2v = *(const float4*)&cp[8],  r3v = *(const float4*)&cp[12];
        float4 i0v = *(const float4*)&cp[64], i1v = *(const float4*)&cp[68];
        float4 i2v = *(const float4*)&cp[72], i3v = *(const float4*)&cp[76];
        y[0]  += xv.x * r0v.x - xv.y * i0v.x;  y[1]  += xv.x * r0v.y - xv.y * i0v.y;
        y[2]  += xv.x * r0v.z - xv.y * i0v.z;  y[3]  += xv.x * r0v.w - xv.y * i0v.w;
        y[4]  += xv.x * r1v.x - xv.y * i1v.x;  y[5]  += xv.x * r1v.y - xv.y * i1v.y;
        y[6]  += xv.x * r1v.z - xv.y * i1v.z;  y[7]  += xv.x * r1v.w - xv.y * i1v.w;
        y[8]  += xv.x * r2v.x - xv.y * i2v.x;  y[9]  += xv.x * r2v.y - xv.y * i2v.y;
        y[10] += xv.x * r2v.z - xv.y * i2v.z;  y[11] += xv.x * r2v.w - xv.y * i2v.w;
        y[12] += xv.x * r3v.x - xv.y * i3v.x;  y[13] += xv.x * r3v.y - xv.y * i3v.y;
        y[14] += xv.x * r3v.z - xv.y * i3v.z;  y[15] += xv.x * r3v.w - xv.y * i3v.w;
    }

    float hrow[16], g[16];
#pragma unroll
    for (int j4 = 0; j4 < 4; ++j4)
        *(float4*)&hrow[j4 * 4] = *(const float4*)&h[(r0 + row) * HD + ucg * 16 + j4 * 4];
    {
        const float* dvp = &Dv[l * HD + ucg * 16];                      // uniform
#pragma unroll
        for (int i = 0; i < 16; ++i) {
            int c = ucg * 16 + i;
            float hnv = hrow[i] * sa[c] + sb[c];
            float t = 2.0f * y[i] + hnv * dvp[i];
            float u2 = 1.5957691216057308f * (t + 0.044715f * t * t * t);
            g[i] = t / (1.0f + __expf(-u2));
        }
    }
    __syncthreads();
#pragma unroll
    for (int j2 = 0; j2 < 8; ++j2)
        *(float2*)&buf[row * 66 + ucg * 16 + 2 * j2] =
            make_float2(g[2 * j2], g[2 * j2 + 1]);
    __syncthreads();

    float uacc[16], sacc[16];
    {
        const float* b1p = &b1[l * HD + ucg * 16];
        const float* b2p = &b2[l * HD + ucg * 16];
#pragma unroll
        for (int j4 = 0; j4 < 4; ++j4) {
            *(float4*)&uacc[j4 * 4] = *(const float4*)&b1p[j4 * 4];
            *(float4*)&sacc[j4 * 4] = *(const float4*)&b2p[j4 * 4];
        }
    }
    for (int k2 = 0; k2 < 32; ++k2) {
        float2 gk = *(float2*)&buf[row * 66 + 2 * k2];
        const float* p1 = &w1t[(size_t)l * 4096 + (2 * k2) * 64 + ucg * 16];  // uniform
        const float* p2 = &w2t[(size_t)l * 4096 + (2 * k2) * 64 + ucg * 16];  // uniform
        float4 a00 = *(const float4*)&p1[0],  a01 = *(const float4*)&p1[4];
        float4 a02 = *(const float4*)&p1[8],  a03 = *(const float4*)&p1[12];
        float4 a10 = *(const float4*)&p1[64], a11 = *(const float4*)&p1[68];
        float4 a12 = *(const float4*)&p1[72], a13 = *(const float4*)&p1[76];
        float4 c00 = *(const float4*)&p2[0],  c01 = *(const float4*)&p2[4];
        float4 c02 = *(const float4*)&p2[8],  c03 = *(const float4*)&p2[12];
        float4 c10 = *(const float4*)&p2[64], c11 = *(const float4*)&p2[68];
        float4 c12 = *(const float4*)&p2[72], c13 = *(const float4*)&p2[76];
        uacc[0]  += gk.x * a00.x + gk.y * a10.x;  uacc[1]  += gk.x * a00.y + gk.y * a10.y;
        uacc[2]  += gk.x * a00.z + gk.y * a10.z;  uacc[3]  += gk.x * a00.w + gk.y * a10.w;
        uacc[4]  += gk.x * a01.x + gk.y * a11.x;  uacc[5]  += gk.x * a01.y + gk.y * a11.y;
        uacc[6]  += gk.x * a01.z + gk.y * a11.z;  uacc[7]  += gk.x * a01.w + gk.y * a11.w;
        uacc[8]  += gk.x * a02.x + gk.y * a12.x;  uacc[9]  += gk.x * a02.y + gk.y * a12.y;
        uacc[10] += gk.x * a02.z + gk.y * a12.z;  uacc[11] += gk.x * a02.w + gk.y * a12.w;
        uacc[12] += gk.x * a03.x + gk.y * a13.x;  uacc[13] += gk.x * a03.y + gk.y * a13.y;
        uacc[14] += gk.x * a03.z + gk.y * a13.z;  uacc[15] += gk.x * a03.w + gk.y * a13.w;
        sacc[0]  += gk.x * c00.x + gk.y * c10.x;  sacc[1]  += gk.x * c00.y + gk.y * c10.y;
        sacc[2]  += gk.x * c00.z + gk.y * c10.z;  sacc[3]  += gk.x * c00.w + gk.y * c10.w;
        sacc[4]  += gk.x * c01.x + gk.y * c11.x;  sacc[5]  += gk.x * c01.y + gk.y * c11.y;
        sacc[6]  += gk.x * c01.z + gk.y * c11.z;  sacc[7]  += gk.x * c01.w + gk.y * c11.w;
        sacc[8]  += gk.x * c02.x + gk.y * c12.x;  sacc[9]  += gk.x * c02.y + gk.y * c12.y;
        sacc[10] += gk.x * c02.z + gk.y * c12.z;  sacc[11] += gk.x * c02.w + gk.y * c12.w;
        sacc[12] += gk.x * c03.x + gk.y * c13.x;  sacc[13] += gk.x * c03.y + gk.y * c13.y;
        sacc[14] += gk.x * c03.z + gk.y * c13.z;  sacc[15] += gk.x * c03.w + gk.y * c13.w;
    }

    if (LAST) {
        const float* dwp0 = &dec_w[ucg * 16];        // uniform
        const float* dwp1 = &dec_w[64 + ucg * 16];   // uniform
        float o0 = 0.0f, o1 = 0.0f;
#pragma unroll
        for (int i = 0; i < 16; ++i) {
            float sg = 1.0f / (1.0f + __expf(-sacc[i]));
            float ho = hrow[i] + uacc[i] * sg;
            o0 += ho * dwp0[i];
            o1 += ho * dwp1[i];
        }
        __syncthreads();
        buf[row * 8 + (wid & 3) * 2]     = o0;
        buf[row * 8 + (wid & 3) * 2 + 1] = o1;
        __syncthreads();
        if (tid < 128) {
            float a0 = buf[tid * 8] + buf[tid * 8 + 2] + buf[tid * 8 + 4] + buf[tid * 8 + 6];
            float a1 = buf[tid * 8 + 1] + buf[tid * 8 + 3] + buf[tid * 8 + 5] + buf[tid * 8 + 7];
            *(float2*)&outp[(r0 + tid) * 2] = make_float2(a0 + dec_b[0], a1 + dec_b[1]);
        }
    } else {
        float ho[16];
#pragma unroll
        for (int i = 0; i < 16; ++i) {
            float sg = 1.0f / (1.0f + __expf(-sacc[i]));
            ho[i] = hrow[i] + uacc[i] * sg;
        }
#pragma unroll
        for (int j4 = 0; j4 < 4; ++j4)
            *(float4*)&hout[(r0 + row) * HD + ucg * 16 + j4 * 4] =
                make_float4(ho[j4 * 4], ho[j4 * 4 + 1], ho[j4 * 4 + 2], ho[j4 * 4 + 3]);
#pragma unroll
        for (int i = 0; i < 16; ++i) {
            float v1 = ho[i], v2 = ho[i] * ho[i];
#pragma unroll
            for (int m = 1; m < 64; m <<= 1) { v1 += __shfl_xor(v1, m, 64); v2 += __shfl_xor(v2, m, 64); }
            if (lane == 0) { sp1[wid * 16 + i] = v1; sp2[wid * 16 + i] = v2; }
        }
        __syncthreads();
        if (tid < 64) {
            atomicAdd(&stats_next[tid],      sp1[tid] + sp1[64 + tid]);
            atomicAdd(&stats_next[64 + tid], sp2[tid] + sp2[64 + tid]);
        }
    }
}

// ---------------------------------------------------------------- launch
extern "C" void kernel_launch(void* const* d_in, const int* in_sizes, int n_in,
                              void* d_out, int out_size, void* d_ws, size_t ws_size,
                              hipStream_t stream)
{
    (void)in_sizes; (void)n_in; (void)out_size; (void)ws_size;
    const float* x     = (const float*)d_in[0];
    const int*   gidx  = (const int*)d_in[1];
    const float* enc_w = (const float*)d_in[2];
    const float* enc_b = (const float*)d_in[3];
    const float* ctx   = (const float*)d_in[4];
    const float* Lre   = (const float*)d_in[5];
    const float* Lim   = (const float*)d_in[6];
    const float* Bre   = (const float*)d_in[7];
    const float* Bim   = (const float*)d_in[8];
    const float* Cre   = (const float*)d_in[9];
    const float* Cim   = (const float*)d_in[10];
    const float* Dv    = (const float*)d_in[11];
    const float* lstep = (const float*)d_in[12];
    const float* nsc   = (const float*)d_in[13];
    const float* nbi   = (const float*)d_in[14];
    const float* w1    = (const float*)d_in[15];
    const float* b1    = (const float*)d_in[16];
    const float* w2    = (const float*)d_in[17];
    const float* b2    = (const float*)d_in[18];
    const float* dw    = (const float*)d_in[19];
    const float* db    = (const float*)d_in[20];
    float* out = (float*)d_out;

    float* ws = (float*)d_ws;
    float* h      = ws;  ws += (size_t)T_LEN * HD;
    float* xs     = ws;  ws += (size_t)T_LEN * HD;
    float* carry  = ws;  ws += (size_t)NBLK * HD;
    float* pc     = ws;  ws += (size_t)NBLK * HD;
    float* stats  = ws;  ws += NLAY * 128;
    float* Lbar   = ws;  ws += NLAY * PD * 2;
    float* Ldt    = ws;  ws += NLAY * PD * 2;
    float* Bbar_t = ws;  ws += NLAY * HD * HD;
    float* Ct     = ws;  ws += NLAY * PD * 128;
    float* w1t    = ws;  ws += NLAY * HD * HD;
    float* w2t    = ws;  ws += NLAY * HD * HD;
    float* wenc   = ws;  ws += IN_DIM * HD;

    ssm_k0_setup<<<1, 512, 0, stream>>>(Lre, Lim, lstep, Bre, Bim, Cre, Cim, w1, w2,
                                        enc_w, gidx, Lbar, Ldt, Bbar_t, Ct, w1t, w2t,
                                        wenc, stats);
    ssm_k1_encoder<<<1024, 512, 0, stream>>>(x, gidx, wenc, enc_b, ctx, h, stats);
    for (int l = 0; l < NLAY; ++l) {
        ssm_k2_bu_scan<<<NBLK, 512, 0, stream>>>(h, stats, nsc, nbi, Bbar_t, Lbar, xs, carry, l);
        ssm_k3_carry<<<PD, 64, 0, stream>>>(carry, Ldt, pc, l);
        if (l < NLAY - 1) {
            ssm_k4_out<false><<<NBLK, 512, 0, stream>>>(
                h, xs, pc, stats, nsc, nbi, Ldt, Ct, Dv, w1t, b1, w2t, b2,
                h, stats + (l + 1) * 128, dw, db, out, l);
        } else {
            ssm_k4_out<true><<<NBLK, 512, 0, stream>>>(
                h, xs, pc, stats, nsc, nbi, Ldt, Ct, Dv, w1t, b1, w2t, b2,
                h, stats, dw, db, out, l);
        }
    }
}